// Round 12
// baseline (68.372 us; speedup 1.0000x reference)
//
#include <hip/hip_runtime.h>

// SoftPixelCNN: out[v, o*64+f] = (1/K) * sum_k exp(-A*d[o,v,k]) * feats[nidx[v,k], f]
// d[o,v,k] = ||(c_v + off_o) - c_n||^2, A = 10*length_scale.
// Offsets (meshgrid-xy order): [0, -e1, -e0, -e2, -e3, +e3, +e2, +e0, +e1].
// NUMERICS: exponentiate the COMBINED exponent (always <= 0) -> no 0*inf NaN.
// r6: wave-uniform ballot skip of neighbours with maxarg < -15 (error ~1.5e-6 << 2.3e-3).
// r9: two vertices per wave (lanes 0-31: v0, 32-63: v1), merged 64-bit ctz mask walk,
//     NT output stores. [41.7 us]
// r12: 2-deep software pipeline (next row gather issued before current FMA block).
//      NO launch_bounds occupancy cap (r11's (256,8) forced VGPR=24 -> remat storm).

#define KNB 32
#define FDIM 64
#define ODIM 9

__global__ __launch_bounds__(256) void spcnn_kernel(
    const float* __restrict__ coords,   // (V,4)
    const float* __restrict__ feats,    // (V,64)
    const int*   __restrict__ nidx,     // (V,32)
    const float* __restrict__ lscale,   // (1,)
    float* __restrict__ out)            // (V,576)
{
    const int lane = threadIdx.x & 63;
    const int v0 = (blockIdx.x * 4 + (threadIdx.x >> 6)) * 2;  // wave owns v0, v0+1
    const int myv = v0 + (lane >> 5);                          // my half's vertex

    const float A = 10.0f * lscale[0];
    // one coalesced 256B load: rows of v0 and v1 are contiguous in nidx
    const int myidx = nidx[v0 * KNB + lane];

    // ---- phase 1 (all lanes useful): exponents for (myv, k=lane&31); 64-bit ballot ----
    const float4 cn = *(const float4*)(coords + (size_t)(unsigned)myidx * 4);
    const float4 cv = *(const float4*)(coords + (size_t)myv * 4);
    const float d0 = cv.x - cn.x, d1 = cv.y - cn.y, d2 = cv.z - cn.z, d3 = cv.w - cn.w;
    const float base = d0*d0 + d1*d1 + d2*d2 + d3*d3;

    const float ex = -A * base;                 // origin-offset exponent
    const float bm = ex - A;                    // minus A*||off||^2 (=1 for axis offsets)
    const float t0 = 2.f*A*d0, t1 = 2.f*A*d1, t2 = 2.f*A*d2, t3 = 2.f*A*d3;

    const float mt = fmaxf(fmaxf(fabsf(t0), fabsf(t1)), fmaxf(fabsf(t2), fabsf(t3)));
    const float maxarg = fmaxf(ex, bm + mt);    // exact max over the 9 exponents
    const bool alive = (maxarg >= -15.0f);
    unsigned long long m = __ballot(alive);     // low 32: v0's keep, high 32: v1's

    float w0=0.f,w1=0.f,w2=0.f,w3=0.f,w4=0.f,w5=0.f,w6=0.f,w7=0.f,w8=0.f;
    if (alive) {
        const float s = 1.0f / (float)KNB;      // fold mean-over-K
        w0 = __expf(ex)      * s;
        w1 = __expf(bm + t1) * s;               // o = -e1
        w2 = __expf(bm + t0) * s;               // o = -e0
        w3 = __expf(bm + t2) * s;               // o = -e2
        w4 = __expf(bm + t3) * s;               // o = -e3
        w5 = __expf(bm - t3) * s;               // o = +e3
        w6 = __expf(bm - t2) * s;               // o = +e2
        w7 = __expf(bm - t0) * s;               // o = +e0
        w8 = __expf(bm - t1) * s;               // o = +e1
    }

    // ---- phase 2: lane = feature f; 2-deep pipelined walk over live neighbours ----
    float a0=0.f,a1=0.f,a2=0.f,a3=0.f,a4=0.f,a5=0.f,a6=0.f,a7=0.f,a8=0.f;  // v0
    float b0=0.f,b1=0.f,b2=0.f,b3=0.f,b4=0.f,b5=0.f,b6=0.f,b7=0.f,b8=0.f;  // v1

    auto PROC = [&](int kk, float gg) {
        const float s0 = __int_as_float(__builtin_amdgcn_readlane(__float_as_int(w0), kk));
        const float s1 = __int_as_float(__builtin_amdgcn_readlane(__float_as_int(w1), kk));
        const float s2 = __int_as_float(__builtin_amdgcn_readlane(__float_as_int(w2), kk));
        const float s3 = __int_as_float(__builtin_amdgcn_readlane(__float_as_int(w3), kk));
        const float s4 = __int_as_float(__builtin_amdgcn_readlane(__float_as_int(w4), kk));
        const float s5 = __int_as_float(__builtin_amdgcn_readlane(__float_as_int(w5), kk));
        const float s6 = __int_as_float(__builtin_amdgcn_readlane(__float_as_int(w6), kk));
        const float s7 = __int_as_float(__builtin_amdgcn_readlane(__float_as_int(w7), kk));
        const float s8 = __int_as_float(__builtin_amdgcn_readlane(__float_as_int(w8), kk));
        if (kk < KNB) {   // wave-uniform branch: which vertex's accumulators
            a0 = fmaf(s0, gg, a0); a1 = fmaf(s1, gg, a1); a2 = fmaf(s2, gg, a2);
            a3 = fmaf(s3, gg, a3); a4 = fmaf(s4, gg, a4); a5 = fmaf(s5, gg, a5);
            a6 = fmaf(s6, gg, a6); a7 = fmaf(s7, gg, a7); a8 = fmaf(s8, gg, a8);
        } else {
            b0 = fmaf(s0, gg, b0); b1 = fmaf(s1, gg, b1); b2 = fmaf(s2, gg, b2);
            b3 = fmaf(s3, gg, b3); b4 = fmaf(s4, gg, b4); b5 = fmaf(s5, gg, b5);
            b6 = fmaf(s6, gg, b6); b7 = fmaf(s7, gg, b7); b8 = fmaf(s8, gg, b8);
        }
    };

    if (m) {
        int k = __builtin_ctzll(m); m &= m - 1;
        float g = feats[(size_t)(unsigned)__builtin_amdgcn_readlane(myidx, k) * FDIM + lane];
        while (m) {
            const int kn = __builtin_ctzll(m); m &= m - 1;
            // issue next row gather BEFORE consuming g -> 1 load always in flight
            const float gn = feats[(size_t)(unsigned)__builtin_amdgcn_readlane(myidx, kn) * FDIM + lane];
            PROC(k, g);
            k = kn; g = gn;
        }
        PROC(k, g);
    }

    // ---- nontemporal stores: write-once stream ----
    float* opa = out + (size_t)v0 * (ODIM * FDIM) + lane;
    __builtin_nontemporal_store(a0, opa + 0*FDIM); __builtin_nontemporal_store(a1, opa + 1*FDIM);
    __builtin_nontemporal_store(a2, opa + 2*FDIM); __builtin_nontemporal_store(a3, opa + 3*FDIM);
    __builtin_nontemporal_store(a4, opa + 4*FDIM); __builtin_nontemporal_store(a5, opa + 5*FDIM);
    __builtin_nontemporal_store(a6, opa + 6*FDIM); __builtin_nontemporal_store(a7, opa + 7*FDIM);
    __builtin_nontemporal_store(a8, opa + 8*FDIM);
    float* opb = out + (size_t)(v0 + 1) * (ODIM * FDIM) + lane;
    __builtin_nontemporal_store(b0, opb + 0*FDIM); __builtin_nontemporal_store(b1, opb + 1*FDIM);
    __builtin_nontemporal_store(b2, opb + 2*FDIM); __builtin_nontemporal_store(b3, opb + 3*FDIM);
    __builtin_nontemporal_store(b4, opb + 4*FDIM); __builtin_nontemporal_store(b5, opb + 5*FDIM);
    __builtin_nontemporal_store(b6, opb + 6*FDIM); __builtin_nontemporal_store(b7, opb + 7*FDIM);
    __builtin_nontemporal_store(b8, opb + 8*FDIM);
}

extern "C" void kernel_launch(void* const* d_in, const int* in_sizes, int n_in,
                              void* d_out, int out_size, void* d_ws, size_t ws_size,
                              hipStream_t stream) {
    const float* coords = (const float*)d_in[0];   // (V,4) f32
    const float* feats  = (const float*)d_in[1];   // (V,64) f32
    // d_in[2] = distsq — unused on the inference path
    const int*   nbidx  = (const int*)d_in[3];     // (V,32) i32
    const float* lscale = (const float*)d_in[4];   // (1,) f32

    const int V = in_sizes[0] / 4;                 // 50000
    // 2 vertices per wave, 4 waves per block -> 8 vertices per block
    spcnn_kernel<<<V / 8, 256, 0, stream>>>(coords, feats, nbidx, lscale, (float*)d_out);
}

// Round 14
// 32.917 us; speedup vs baseline: 2.0771x; 2.0771x over previous
//
#include <hip/hip_runtime.h>

// SoftPixelCNN: out[v, o*64+f] = (1/K) * sum_k exp(-A*d[o,v,k]) * feats[nidx[v,k], f]
// d[o,v,k] = ||(c_v + off_o) - c_n||^2, A = 10*length_scale.
// Offsets (meshgrid-xy order): [0, -e1, -e0, -e2, -e3, +e3, +e2, +e0, +e1].
// NUMERICS: exponentiate the COMBINED exponent (always <= 0) -> no 0*inf NaN.
// r6/r10: wave-uniform ballot skip, threshold -12 (dropped contribution ~3e-5 << 2.3e-3).
// r9: two vertices per wave (lanes 0-31: v0, 32-63: v1), NT output stores. [41.7 us]
// r13 lesson: cross-kernel producer->consumer via d_ws diverges under graph replay
//     (per-XCD L2 + 0xAA poison) -> compaction must stay within one kernel/wave.
// r14: per-wave LDS compaction of live {w0..w8, idx} records (48B, b128-aligned),
//      then COUNTED loops (uniform trip count, no mask-walk PHIs) so the compiler
//      can hoist next-record ds_reads + row gather above current FMAs.

#define KNB 32
#define FDIM 64
#define ODIM 9
typedef unsigned int u32;

__global__ __launch_bounds__(256) void spcnn_kernel(
    const float* __restrict__ coords,   // (V,4)
    const float* __restrict__ feats,    // (V,64)
    const int*   __restrict__ nidx,     // (V,32)
    const float* __restrict__ lscale,   // (1,)
    float* __restrict__ out)            // (V,576)
{
    // per-warp record arena: 64 records x 12 dwords (48B, keeps b128 alignment)
    __shared__ __align__(16) float wlds[4][64][12];   // 12.3 KB / block
    const int lane = threadIdx.x & 63;
    const int warp = threadIdx.x >> 6;
    const int v0 = (blockIdx.x * 4 + warp) * 2;       // wave owns v0, v0+1
    const int half = lane >> 5;
    const int myv = v0 + half;

    const float A = 10.0f * lscale[0];
    const int myidx = nidx[v0 * KNB + lane];          // coalesced 256B (both rows)

    // ---- phase 1: exponents for (myv, k=lane&31); ballot; compact to LDS ----
    const float4 cn = *(const float4*)(coords + (size_t)(u32)myidx * 4);
    const float4 cv = *(const float4*)(coords + (size_t)myv * 4);
    const float d0 = cv.x - cn.x, d1 = cv.y - cn.y, d2 = cv.z - cn.z, d3 = cv.w - cn.w;
    const float base = d0*d0 + d1*d1 + d2*d2 + d3*d3;

    const float ex = -A * base;                 // origin-offset exponent
    const float bm = ex - A;                    // minus A*||off||^2 (=1 for axis offsets)
    const float t0 = 2.f*A*d0, t1 = 2.f*A*d1, t2 = 2.f*A*d2, t3 = 2.f*A*d3;
    const float mt = fmaxf(fmaxf(fabsf(t0), fabsf(t1)), fmaxf(fabsf(t2), fabsf(t3)));
    const bool alive = (fmaxf(ex, bm + mt) >= -12.0f);

    const unsigned long long m = __ballot(alive);     // low 32: v0, high 32: v1
    const u32 mlo = (u32)m, mhi = (u32)(m >> 32);
    const int na = __builtin_popcount(mlo);           // live count, v0 (uniform)
    const int nb = __builtin_popcount(mhi);           // live count, v1 (uniform)

    if (alive) {
        const float s = 1.0f / (float)KNB;            // fold mean-over-K
        const float w0 = __expf(ex)      * s;
        const float w1 = __expf(bm + t1) * s;         // o = -e1
        const float w2 = __expf(bm + t0) * s;         // o = -e0
        const float w3 = __expf(bm + t2) * s;         // o = -e2
        const float w4 = __expf(bm + t3) * s;         // o = -e3
        const float w5 = __expf(bm - t3) * s;         // o = +e3
        const float w6 = __expf(bm - t2) * s;         // o = +e2
        const float w7 = __expf(bm - t0) * s;         // o = +e0
        const float w8 = __expf(bm - t1) * s;         // o = +e1

        const u32 hm = half ? mhi : mlo;
        const int rank = __builtin_popcount(hm & ((1u << (lane & 31)) - 1u));
        float* rec = wlds[warp][half * 32 + rank];
        *(float4*)(rec)     = make_float4(w0, w1, w2, w3);   // ds_write_b128
        *(float4*)(rec + 4) = make_float4(w4, w5, w6, w7);   // ds_write_b128
        rec[8] = w8;
        ((u32*)rec)[9] = (u32)myidx;
    }
    // same-wave LDS write->read: DS ops in order per wave; compiler inserts lgkmcnt

    // ---- phase 2: counted loops over compacted records (lane = feature f) ----
    float a0=0.f,a1=0.f,a2=0.f,a3=0.f,a4=0.f,a5=0.f,a6=0.f,a7=0.f,a8=0.f;  // v0
    float b0=0.f,b1=0.f,b2=0.f,b3=0.f,b4=0.f,b5=0.f,b6=0.f,b7=0.f,b8=0.f;  // v1

    #pragma unroll 2
    for (int r = 0; r < na; ++r) {
        const float* rec = wlds[warp][r];
        const float4 wa = *(const float4*)rec;        // broadcast ds_read_b128
        const float4 wb = *(const float4*)(rec + 4);  // broadcast ds_read_b128
        const float2 wc = *(const float2*)(rec + 8);  // broadcast ds_read_b64 (w8, idx)
        const u32 idx = __float_as_uint(wc.y);
        const float g = feats[(size_t)idx * FDIM + lane];  // coalesced 256B row
        a0 = fmaf(wa.x, g, a0); a1 = fmaf(wa.y, g, a1); a2 = fmaf(wa.z, g, a2);
        a3 = fmaf(wa.w, g, a3); a4 = fmaf(wb.x, g, a4); a5 = fmaf(wb.y, g, a5);
        a6 = fmaf(wb.z, g, a6); a7 = fmaf(wb.w, g, a7); a8 = fmaf(wc.x, g, a8);
    }
    #pragma unroll 2
    for (int r = 0; r < nb; ++r) {
        const float* rec = wlds[warp][32 + r];
        const float4 wa = *(const float4*)rec;
        const float4 wb = *(const float4*)(rec + 4);
        const float2 wc = *(const float2*)(rec + 8);
        const u32 idx = __float_as_uint(wc.y);
        const float g = feats[(size_t)idx * FDIM + lane];
        b0 = fmaf(wa.x, g, b0); b1 = fmaf(wa.y, g, b1); b2 = fmaf(wa.z, g, b2);
        b3 = fmaf(wa.w, g, b3); b4 = fmaf(wb.x, g, b4); b5 = fmaf(wb.y, g, b5);
        b6 = fmaf(wb.z, g, b6); b7 = fmaf(wb.w, g, b7); b8 = fmaf(wc.x, g, b8);
    }

    // ---- nontemporal stores: write-once stream ----
    float* opa = out + (size_t)v0 * (ODIM * FDIM) + lane;
    __builtin_nontemporal_store(a0, opa + 0*FDIM); __builtin_nontemporal_store(a1, opa + 1*FDIM);
    __builtin_nontemporal_store(a2, opa + 2*FDIM); __builtin_nontemporal_store(a3, opa + 3*FDIM);
    __builtin_nontemporal_store(a4, opa + 4*FDIM); __builtin_nontemporal_store(a5, opa + 5*FDIM);
    __builtin_nontemporal_store(a6, opa + 6*FDIM); __builtin_nontemporal_store(a7, opa + 7*FDIM);
    __builtin_nontemporal_store(a8, opa + 8*FDIM);
    float* opb = out + (size_t)(v0 + 1) * (ODIM * FDIM) + lane;
    __builtin_nontemporal_store(b0, opb + 0*FDIM); __builtin_nontemporal_store(b1, opb + 1*FDIM);
    __builtin_nontemporal_store(b2, opb + 2*FDIM); __builtin_nontemporal_store(b3, opb + 3*FDIM);
    __builtin_nontemporal_store(b4, opb + 4*FDIM); __builtin_nontemporal_store(b5, opb + 5*FDIM);
    __builtin_nontemporal_store(b6, opb + 6*FDIM); __builtin_nontemporal_store(b7, opb + 7*FDIM);
    __builtin_nontemporal_store(b8, opb + 8*FDIM);
}

extern "C" void kernel_launch(void* const* d_in, const int* in_sizes, int n_in,
                              void* d_out, int out_size, void* d_ws, size_t ws_size,
                              hipStream_t stream) {
    const float* coords = (const float*)d_in[0];   // (V,4) f32
    const float* feats  = (const float*)d_in[1];   // (V,64) f32
    // d_in[2] = distsq — unused on the inference path
    const int*   nbidx  = (const int*)d_in[3];     // (V,32) i32
    const float* lscale = (const float*)d_in[4];   // (1,) f32

    const int V = in_sizes[0] / 4;                 // 50000
    // 2 vertices per wave, 4 waves per block -> 8 vertices per block
    spcnn_kernel<<<V / 8, 256, 0, stream>>>(coords, feats, nbidx, lscale, (float*)d_out);
}

// Round 15
// 32.773 us; speedup vs baseline: 2.0862x; 1.0044x over previous
//
#include <hip/hip_runtime.h>

// SoftPixelCNN: out[v, o*64+f] = (1/K) * sum_k exp(-A*d[o,v,k]) * feats[nidx[v,k], f]
// d[o,v,k] = ||(c_v + off_o) - c_n||^2, A = 10*length_scale.
// Offsets (meshgrid-xy order): [0, -e1, -e0, -e2, -e3, +e3, +e2, +e0, +e1].
// NUMERICS: exponentiate the COMBINED exponent (always <= 0) -> no 0*inf NaN.
// r6/r10: wave-uniform ballot skip, threshold -12 (dropped contribution ~3e-5 << 2.3e-3).
// r9: two vertices per wave (lanes 0-31: v0, 32-63: v1), NT output stores.
// r14: per-wave LDS compaction + COUNTED loops -> compiler pipelines. [32.9 us]
// r15: pad both halves to nmax with zero-weight/idx-0 dummy records, then ONE
//      branch-free merged loop doing a v0-record AND a v1-record per iteration:
//      2 independent gathers/iter (x2 unroll = 4 in flight) -> double MLP, zero branches.

#define KNB 32
#define FDIM 64
#define ODIM 9
typedef unsigned int u32;

__global__ __launch_bounds__(256) void spcnn_kernel(
    const float* __restrict__ coords,   // (V,4)
    const float* __restrict__ feats,    // (V,64)
    const int*   __restrict__ nidx,     // (V,32)
    const float* __restrict__ lscale,   // (1,)
    float* __restrict__ out)            // (V,576)
{
    // per-warp record arena: 64 records x 12 dwords (48B, b128-aligned)
    __shared__ __align__(16) float wlds[4][64][12];   // 12.3 KB / block
    const int lane = threadIdx.x & 63;
    const int warp = threadIdx.x >> 6;
    const int v0 = (blockIdx.x * 4 + warp) * 2;       // wave owns v0, v0+1
    const int half = lane >> 5;
    const int j = lane & 31;                          // my k within my half
    const int myv = v0 + half;

    const float A = 10.0f * lscale[0];
    const int myidx = nidx[v0 * KNB + lane];          // coalesced 256B (both rows)

    // ---- phase 1: exponents for (myv, k=j); ballot; compact to LDS ----
    const float4 cn = *(const float4*)(coords + (size_t)(u32)myidx * 4);
    const float4 cv = *(const float4*)(coords + (size_t)myv * 4);
    const float d0 = cv.x - cn.x, d1 = cv.y - cn.y, d2 = cv.z - cn.z, d3 = cv.w - cn.w;
    const float base = d0*d0 + d1*d1 + d2*d2 + d3*d3;

    const float ex = -A * base;                 // origin-offset exponent
    const float bm = ex - A;                    // minus A*||off||^2 (=1 for axis offsets)
    const float t0 = 2.f*A*d0, t1 = 2.f*A*d1, t2 = 2.f*A*d2, t3 = 2.f*A*d3;
    const float mt = fmaxf(fmaxf(fabsf(t0), fabsf(t1)), fmaxf(fabsf(t2), fabsf(t3)));
    const bool alive = (fmaxf(ex, bm + mt) >= -12.0f);

    const unsigned long long m = __ballot(alive);     // low 32: v0, high 32: v1
    const u32 mlo = (u32)m, mhi = (u32)(m >> 32);
    const int na = __builtin_popcount(mlo);           // live count v0 (uniform)
    const int nb = __builtin_popcount(mhi);           // live count v1 (uniform)
    const int myn = half ? nb : na;
    const int nmax = na > nb ? na : nb;

    // dummy records at slots [myn, 32): zero weights, idx 0 (row-0 gather is L2-hot)
    {
        float* zp = wlds[warp][half * 32 + j];
        if (j >= myn) {
            const float4 z4 = make_float4(0.f, 0.f, 0.f, 0.f);
            *(float4*)(zp)     = z4;
            *(float4*)(zp + 4) = z4;
            *(float2*)(zp + 8) = make_float2(0.f, 0.f);   // w8=0, idx=0
        }
    }
    if (alive) {
        const float s = 1.0f / (float)KNB;            // fold mean-over-K
        const float w0 = __expf(ex)      * s;
        const float w1 = __expf(bm + t1) * s;         // o = -e1
        const float w2 = __expf(bm + t0) * s;         // o = -e0
        const float w3 = __expf(bm + t2) * s;         // o = -e2
        const float w4 = __expf(bm + t3) * s;         // o = -e3
        const float w5 = __expf(bm - t3) * s;         // o = +e3
        const float w6 = __expf(bm - t2) * s;         // o = +e2
        const float w7 = __expf(bm - t0) * s;         // o = +e0
        const float w8 = __expf(bm - t1) * s;         // o = +e1

        const u32 hm = half ? mhi : mlo;
        const int rank = __builtin_popcount(hm & ((1u << j) - 1u));   // < myn, no overlap
        float* rec = wlds[warp][half * 32 + rank];
        *(float4*)(rec)     = make_float4(w0, w1, w2, w3);   // ds_write_b128
        *(float4*)(rec + 4) = make_float4(w4, w5, w6, w7);   // ds_write_b128
        *(float2*)(rec + 8) = make_float2(w8, __uint_as_float((u32)myidx));
    }
    // same-wave LDS write->read: DS ops in order per wave; compiler inserts lgkmcnt

    // ---- phase 2: ONE branch-free counted loop, one record from EACH half/iter ----
    float a0=0.f,a1=0.f,a2=0.f,a3=0.f,a4=0.f,a5=0.f,a6=0.f,a7=0.f,a8=0.f;  // v0
    float b0=0.f,b1=0.f,b2=0.f,b3=0.f,b4=0.f,b5=0.f,b6=0.f,b7=0.f,b8=0.f;  // v1

    #pragma unroll 2
    for (int r = 0; r < nmax; ++r) {
        const float* recA = wlds[warp][r];
        const float* recB = wlds[warp][32 + r];
        const float4 waA = *(const float4*)recA;          // broadcast ds_read_b128
        const float4 wbA = *(const float4*)(recA + 4);
        const float2 wcA = *(const float2*)(recA + 8);    // (w8, idx)
        const float4 waB = *(const float4*)recB;
        const float4 wbB = *(const float4*)(recB + 4);
        const float2 wcB = *(const float2*)(recB + 8);
        const u32 idxA = __float_as_uint(wcA.y);
        const u32 idxB = __float_as_uint(wcB.y);
        const float gA = feats[(size_t)idxA * FDIM + lane];   // 2 independent gathers
        const float gB = feats[(size_t)idxB * FDIM + lane];
        a0 = fmaf(waA.x, gA, a0); a1 = fmaf(waA.y, gA, a1); a2 = fmaf(waA.z, gA, a2);
        a3 = fmaf(waA.w, gA, a3); a4 = fmaf(wbA.x, gA, a4); a5 = fmaf(wbA.y, gA, a5);
        a6 = fmaf(wbA.z, gA, a6); a7 = fmaf(wbA.w, gA, a7); a8 = fmaf(wcA.x, gA, a8);
        b0 = fmaf(waB.x, gB, b0); b1 = fmaf(waB.y, gB, b1); b2 = fmaf(waB.z, gB, b2);
        b3 = fmaf(waB.w, gB, b3); b4 = fmaf(wbB.x, gB, b4); b5 = fmaf(wbB.y, gB, b5);
        b6 = fmaf(wbB.z, gB, b6); b7 = fmaf(wbB.w, gB, b7); b8 = fmaf(wcB.x, gB, b8);
    }

    // ---- nontemporal stores: write-once stream ----
    float* opa = out + (size_t)v0 * (ODIM * FDIM) + lane;
    __builtin_nontemporal_store(a0, opa + 0*FDIM); __builtin_nontemporal_store(a1, opa + 1*FDIM);
    __builtin_nontemporal_store(a2, opa + 2*FDIM); __builtin_nontemporal_store(a3, opa + 3*FDIM);
    __builtin_nontemporal_store(a4, opa + 4*FDIM); __builtin_nontemporal_store(a5, opa + 5*FDIM);
    __builtin_nontemporal_store(a6, opa + 6*FDIM); __builtin_nontemporal_store(a7, opa + 7*FDIM);
    __builtin_nontemporal_store(a8, opa + 8*FDIM);
    float* opb = out + (size_t)(v0 + 1) * (ODIM * FDIM) + lane;
    __builtin_nontemporal_store(b0, opb + 0*FDIM); __builtin_nontemporal_store(b1, opb + 1*FDIM);
    __builtin_nontemporal_store(b2, opb + 2*FDIM); __builtin_nontemporal_store(b3, opb + 3*FDIM);
    __builtin_nontemporal_store(b4, opb + 4*FDIM); __builtin_nontemporal_store(b5, opb + 5*FDIM);
    __builtin_nontemporal_store(b6, opb + 6*FDIM); __builtin_nontemporal_store(b7, opb + 7*FDIM);
    __builtin_nontemporal_store(b8, opb + 8*FDIM);
}

extern "C" void kernel_launch(void* const* d_in, const int* in_sizes, int n_in,
                              void* d_out, int out_size, void* d_ws, size_t ws_size,
                              hipStream_t stream) {
    const float* coords = (const float*)d_in[0];   // (V,4) f32
    const float* feats  = (const float*)d_in[1];   // (V,64) f32
    // d_in[2] = distsq — unused on the inference path
    const int*   nbidx  = (const int*)d_in[3];     // (V,32) i32
    const float* lscale = (const float*)d_in[4];   // (1,) f32

    const int V = in_sizes[0] / 4;                 // 50000
    // 2 vertices per wave, 4 waves per block -> 8 vertices per block
    spcnn_kernel<<<V / 8, 256, 0, stream>>>(coords, feats, nbidx, lscale, (float*)d_out);
}